// Round 13
// baseline (1824.851 us; speedup 1.0000x reference)
//
#include <hip/hip_runtime.h>
#include <hip/hip_bf16.h>
#include <math.h>

#define BB 4
#define TT 2048
#define DD 256
#define FF 1024
#define NL 4
#define NB 512            // persistent grid: 512 blocks x 256 thr = 2 blocks/CU

typedef __bf16 bf16x8 __attribute__((ext_vector_type(8)));
typedef float f32x4 __attribute__((ext_vector_type(4)));
typedef __hip_bfloat16 bf16;

__device__ __forceinline__ void stage16(const bf16* gp, bf16* lp) {
  __builtin_amdgcn_global_load_lds(
      (const __attribute__((address_space(1))) unsigned int*)gp,
      (__attribute__((address_space(3))) unsigned int*)lp, 16, 0, 0);
}

__device__ __forceinline__ float gelu_f(float v) {
  float x = fabsf(v) * 0.70710678118654752f;
  float t = 1.0f / fmaf(0.3275911f, x, 1.0f);
  float p = t * fmaf(t, fmaf(t, fmaf(t, fmaf(t, 1.061405429f, -1.453152027f),
                                     1.421413741f), -0.284496736f), 0.254829592f);
  float erfv = copysignf(1.0f - p * __expf(-x * x), v);
  return 0.5f * v * (1.0f + erfv);
}

// device-scope grid barrier: bar[0]=count, bar[1]=generation (zeroed per launch)
__device__ __forceinline__ void gbar(unsigned* bar) {
  __syncthreads();
  if (threadIdx.x == 0) {
    __threadfence();                               // release my stores (wb L2)
    unsigned g = atomicAdd(bar + 1, 0u);           // read gen (atomic load)
    if (atomicAdd(bar, 1u) == NB - 1) {
      atomicExch(bar, 0u);
      __threadfence();
      atomicAdd(bar + 1, 1u);                      // flip generation
    } else {
      while (atomicAdd(bar + 1, 0u) == g) __builtin_amdgcn_s_sleep(1);
    }
    __threadfence();                               // acquire (inv stale L2)
  }
  __syncthreads();
}

// ---- GEMM stage: C = act(A@B^T + bias); tile 32MWx32NW, BK=64 ----
template <int MW, int NW, int KTOT, int ACT, int OUTF>
__device__ __forceinline__ void gemm_stage(
    char* smraw, int bid, int nTiles,
    const bf16* __restrict__ A, const bf16* __restrict__ B,
    const float* __restrict__ bias, void* __restrict__ Cout, int N) {
  constexpr int BM = 32 * MW, BN = 32 * NW, ROWS = BM + BN;
  constexpr int CHB = ROWS * 32;
  constexpr int RG = ROWS / 16;
  constexpr int NST = 2 * RG;
  bf16* sm = (bf16*)smraw;
  const int tid = threadIdx.x;
  const int wave = tid >> 6, lane = tid & 63;
  const int m0 = (bid / nTiles) * BM, n0 = (bid % nTiles) * BN;
  const int wm = (wave >> 1) * (16 * MW), wn = (wave & 1) * (16 * NW);
  const int quad = lane >> 4, lr = lane & 15;
  const int srow = lane >> 2, scol = (lane & 3) * 8;

  f32x4 acc[MW][NW] = {};

  for (int kt = 0; kt < KTOT; kt += 64) {
    __syncthreads();
#pragma unroll
    for (int i = 0; i < (NST + 3) / 4; ++i) {
      int inst = i * 4 + wave;
      if (inst < NST) {
        int c = inst / RG, grp = inst - c * RG;
        int r = grp * 16 + srow;
        const bf16* gp =
            (r < BM) ? (A + (size_t)(m0 + r) * KTOT + kt + c * 32 + scol)
                     : (B + (size_t)(n0 + (r - BM)) * KTOT + kt + c * 32 + scol);
        stage16(gp, sm + c * CHB + grp * 512);
      }
    }
    __syncthreads();
#pragma unroll
    for (int c = 0; c < 2; ++c) {
      bf16x8 af[MW], bfr[NW];
#pragma unroll
      for (int mi = 0; mi < MW; ++mi)
        af[mi] = *(const bf16x8*)(sm + c * CHB + (wm + mi * 16 + lr) * 32 + quad * 8);
#pragma unroll
      for (int ni = 0; ni < NW; ++ni)
        bfr[ni] = *(const bf16x8*)(sm + c * CHB + (BM + wn + ni * 16 + lr) * 32 + quad * 8);
#pragma unroll
      for (int mi = 0; mi < MW; ++mi)
#pragma unroll
        for (int ni = 0; ni < NW; ++ni)
          acc[mi][ni] = __builtin_amdgcn_mfma_f32_16x16x32_bf16(
              af[mi], bfr[ni], acc[mi][ni], 0, 0, 0);
    }
  }

#pragma unroll
  for (int mi = 0; mi < MW; ++mi)
#pragma unroll
    for (int ni = 0; ni < NW; ++ni) {
      int col = n0 + wn + ni * 16 + lr;
      float bv = bias[col];
#pragma unroll
      for (int r = 0; r < 4; ++r) {
        int row = m0 + wm + mi * 16 + quad * 4 + r;
        float v = acc[mi][ni][r] + bv;
        if (ACT == 1) v = gelu_f(v);
        if (OUTF) ((float*)Cout)[(size_t)row * N + col] = v;
        else ((bf16*)Cout)[(size_t)row * N + col] = __float2bfloat16(v);
      }
    }
}

// ---- Wo + residual + LN stage: BM=16 full-row (N=256), K=256 ----
__device__ __forceinline__ void woln_stage(
    char* smraw, int bid, const bf16* __restrict__ A, const bf16* __restrict__ B,
    const float* __restrict__ bias, const float* __restrict__ res,
    const float* __restrict__ g, const float* __restrict__ bb,
    float* __restrict__ xout, bf16* __restrict__ yout) {
  constexpr int ROWS = 16 + 256, CHB = ROWS * 32, RG = ROWS / 16, NST = 2 * RG; // 34
  bf16* sm = (bf16*)smraw;
  float* red1 = (float*)(smraw + 34816);
  float* red2 = (float*)(smraw + 35072);
  const int tid = threadIdx.x;
  const int wave = tid >> 6, lane = tid & 63;
  const int quad = lane >> 4, lr = lane & 15;
  const int m0 = bid * 16;
  const int srow = lane >> 2, scol = (lane & 3) * 8;

  f32x4 acc[4] = {};
  for (int kt = 0; kt < 256; kt += 64) {
    __syncthreads();
#pragma unroll
    for (int i = 0; i < 9; ++i) {
      int inst = i * 4 + wave;
      if (inst < NST) {
        int c = inst / RG, grp = inst - c * RG;
        int r = grp * 16 + srow;
        const bf16* gp =
            (r < 16) ? (A + (size_t)(m0 + r) * 256 + kt + c * 32 + scol)
                     : (B + (size_t)(r - 16) * 256 + kt + c * 32 + scol);
        stage16(gp, sm + c * CHB + grp * 512);
      }
    }
    __syncthreads();
#pragma unroll
    for (int c = 0; c < 2; ++c) {
      bf16x8 af = *(const bf16x8*)(sm + c * CHB + lr * 32 + quad * 8);
      bf16x8 bfr[4];
#pragma unroll
      for (int ni = 0; ni < 4; ++ni)
        bfr[ni] = *(const bf16x8*)(sm + c * CHB + (16 + wave * 64 + ni * 16 + lr) * 32 + quad * 8);
#pragma unroll
      for (int ni = 0; ni < 4; ++ni)
        acc[ni] = __builtin_amdgcn_mfma_f32_16x16x32_bf16(af, bfr[ni], acc[ni], 0, 0, 0);
    }
  }

  float v[4][4];
  float s1[4] = {}, s2[4] = {};
#pragma unroll
  for (int ni = 0; ni < 4; ++ni) {
    int col = wave * 64 + ni * 16 + lr;
    float bv = bias[col];
#pragma unroll
    for (int r = 0; r < 4; ++r) {
      int row = m0 + quad * 4 + r;
      float val = acc[ni][r] + bv + res[(size_t)row * DD + col];
      v[ni][r] = val;
      s1[r] += val;
      s2[r] = fmaf(val, val, s2[r]);
    }
  }
#pragma unroll
  for (int r = 0; r < 4; ++r) {
#pragma unroll
    for (int off = 8; off; off >>= 1) {
      s1[r] += __shfl_xor(s1[r], off, 64);
      s2[r] += __shfl_xor(s2[r], off, 64);
    }
  }
  if (lr == 0) {
#pragma unroll
    for (int r = 0; r < 4; ++r) {
      red1[wave * 16 + quad * 4 + r] = s1[r];
      red2[wave * 16 + quad * 4 + r] = s2[r];
    }
  }
  __syncthreads();
#pragma unroll
  for (int r = 0; r < 4; ++r) {
    int rl = quad * 4 + r;
    float ssum = red1[rl] + red1[16 + rl] + red1[32 + rl] + red1[48 + rl];
    float qsum = red2[rl] + red2[16 + rl] + red2[32 + rl] + red2[48 + rl];
    float mu = ssum * (1.f / DD);
    float var = qsum * (1.f / DD) - mu * mu;
    float rr = rsqrtf(var + 1e-5f);
    int row = m0 + rl;
#pragma unroll
    for (int ni = 0; ni < 4; ++ni) {
      int col = wave * 64 + ni * 16 + lr;
      float y = (v[ni][r] - mu) * rr * g[col] + bb[col];
      yout[(size_t)row * DD + col] = __float2bfloat16(y);
      xout[(size_t)row * DD + col] = v[ni][r];
    }
  }
}

// ---- attention stage: bid -> (tq tile = bid&31, bh = bid>>5) ----
__device__ __forceinline__ void attn_stage(char* smraw, int bid,
                                           const bf16* __restrict__ qkv,
                                           bf16* __restrict__ o) {
  bf16* KsPs = (bf16*)smraw;                 // 128x72 (18432 B) then P 64x136
  bf16* Vt = (bf16*)(smraw + 18432);         // 64x136 (17408 B)
  const int bh = bid >> 5;
  const int b = bh >> 2, h = bh & 3;
  const int t0 = (bid & 31) * 64;
  const int sbase = t0 - 63;
  const int tid = threadIdx.x;

  const bf16* kb = qkv + (size_t)(b * TT) * 768 + 256 + h * 64;
  const bf16* vb = kb + 256;
  union U8 { uint4 u; bf16 hx[8]; };
#pragma unroll
  for (int it = 0; it < 4; ++it) {
    int f = tid + it * 256;
    int si = f >> 3;
    int c8 = f & 7;
    int s = sbase + si;
    U8 kr, vr;
    kr.u = make_uint4(0, 0, 0, 0); vr.u = make_uint4(0, 0, 0, 0);
    if (s >= 0 && s < TT) {
      kr.u = *(const uint4*)&kb[(size_t)s * 768 + 8 * c8];
      vr.u = *(const uint4*)&vb[(size_t)s * 768 + 8 * c8];
    }
    *(uint4*)&KsPs[si * 72 + c8 * 8] = kr.u;
    int pc = (si >> 3) ^ c8;
#pragma unroll
    for (int j = 0; j < 8; ++j) Vt[(c8 * 8 + j) * 136 + pc * 8 + (si & 7)] = vr.hx[j];
  }
  __syncthreads();

  const int wave = tid >> 6, lane = tid & 63;
  const int quad = lane >> 4, lr = lane & 15;

  const bf16* qrow = qkv + (size_t)(b * TT + t0 + wave * 16 + lr) * 768 + h * 64;
  bf16x8 qa0 = *(const bf16x8*)(qrow + quad * 8);
  bf16x8 qa1 = *(const bf16x8*)(qrow + 32 + quad * 8);
  f32x4 sc[8];
#pragma unroll
  for (int c = 0; c < 8; ++c) {
    f32x4 a = {};
    bf16x8 kf0 = *(const bf16x8*)&KsPs[(c * 16 + lr) * 72 + quad * 8];
    a = __builtin_amdgcn_mfma_f32_16x16x32_bf16(qa0, kf0, a, 0, 0, 0);
    bf16x8 kf1 = *(const bf16x8*)&KsPs[(c * 16 + lr) * 72 + 32 + quad * 8];
    a = __builtin_amdgcn_mfma_f32_16x16x32_bf16(qa1, kf1, a, 0, 0, 0);
    sc[c] = a;
  }
  __syncthreads();

#pragma unroll
  for (int reg = 0; reg < 4; ++reg) {
    int dt = wave * 16 + quad * 4 + reg;
    float pv[8];
    float mx = -1e30f;
#pragma unroll
    for (int c = 0; c < 8; ++c) {
      int si = c * 16 + lr;
      float v = sc[c][reg] * 0.125f;
      bool ok = (si >= dt) && (si <= dt + 63) && (sbase + si >= 0);
      v = ok ? v : -1e30f;
      pv[c] = v;
      mx = fmaxf(mx, v);
    }
#pragma unroll
    for (int off = 8; off; off >>= 1) mx = fmaxf(mx, __shfl_xor(mx, off, 64));
    float l = 0.f;
#pragma unroll
    for (int c = 0; c < 8; ++c) { float e = __expf(pv[c] - mx); pv[c] = e; l += e; }
#pragma unroll
    for (int off = 8; off; off >>= 1) l += __shfl_xor(l, off, 64);
    float rinv = 1.f / l;
#pragma unroll
    for (int c = 0; c < 8; ++c)
      KsPs[(wave * 16 + quad * 4 + reg) * 136 + c * 16 + lr] = __float2bfloat16(pv[c] * rinv);
  }

  bf16* obase = o + (size_t)(b * TT) * DD + h * 64;
#pragma unroll
  for (int ct = 0; ct < 4; ++ct) {
    f32x4 acc = {};
#pragma unroll
    for (int kk = 0; kk < 4; ++kk) {
      bf16x8 pa = *(const bf16x8*)&KsPs[(wave * 16 + lr) * 136 + kk * 32 + quad * 8];
      int dd = ct * 16 + lr;
      bf16x8 vf = *(const bf16x8*)&Vt[dd * 136 + (((kk * 4 + quad) ^ (dd >> 3)) * 8)];
      acc = __builtin_amdgcn_mfma_f32_16x16x32_bf16(pa, vf, acc, 0, 0, 0);
    }
#pragma unroll
    for (int reg = 0; reg < 4; ++reg) {
      int t = t0 + wave * 16 + quad * 4 + reg;
      obase[(size_t)t * DD + ct * 16 + lr] = __float2bfloat16(acc[reg]);
    }
  }
}

// ---- residual + LN stage: 16 rows/block, 4 rows/wave ----
template <int FIN>
__device__ __forceinline__ void rln_stage(
    int bid, const float* __restrict__ go, const float* __restrict__ xin,
    const float* __restrict__ g, const float* __restrict__ b,
    float* __restrict__ xout, bf16* __restrict__ sbout, float* __restrict__ out) {
  const int wave = threadIdx.x >> 6, lane = threadIdx.x & 63;
#pragma unroll
  for (int rr = 0; rr < 4; ++rr) {
    int row = bid * 16 + wave * 4 + rr;
    const float* gr = go + (size_t)row * DD;
    const float* xr = xin + (size_t)row * DD;
    float v[4];
    float s = 0.f;
#pragma unroll
    for (int i = 0; i < 4; ++i) {
      int d = lane + 64 * i;
      v[i] = gr[d] + xr[d];
      s += v[i];
    }
#pragma unroll
    for (int off = 32; off; off >>= 1) s += __shfl_xor(s, off, 64);
    float mu = s * (1.f / DD);
    float vs = 0.f;
#pragma unroll
    for (int i = 0; i < 4; ++i) { float dd = v[i] - mu; vs = fmaf(dd, dd, vs); }
#pragma unroll
    for (int off = 32; off; off >>= 1) vs += __shfl_xor(vs, off, 64);
    float rr2 = rsqrtf(vs * (1.f / DD) + 1e-5f);
#pragma unroll
    for (int i = 0; i < 4; ++i) {
      int d = lane + 64 * i;
      float y = (v[i] - mu) * rr2 * g[d] + b[d];
      if (FIN) {
        out[(size_t)row * DD + d] = y;
      } else {
        xout[(size_t)row * DD + d] = v[i];
        sbout[(size_t)row * DD + d] = __float2bfloat16(y);
      }
    }
  }
}

// ---- the whole forward pass, one dispatch ----
__global__ __launch_bounds__(256, 2) void mega_kernel(
    const float4* __restrict__ Wq4, const float4* __restrict__ Wo4,
    const float4* __restrict__ W14, const float4* __restrict__ W24,
    const float* __restrict__ tokens,
    const float* __restrict__ bqkv, const float* __restrict__ bo,
    const float* __restrict__ b1, const float* __restrict__ b2,
    const float* __restrict__ ln1g, const float* __restrict__ ln1b,
    const float* __restrict__ ln2g, const float* __restrict__ ln2b,
    const float* __restrict__ lnfg, const float* __restrict__ lnfb,
    float* __restrict__ x, bf16* __restrict__ sb, bf16* __restrict__ big,
    ushort4* __restrict__ wdst, float* __restrict__ gbuf,
    float* __restrict__ out, unsigned* __restrict__ bar) {
  __shared__ __align__(16) char sm[36864];
  const int bid = blockIdx.x;
  const int tid = threadIdx.x;

  // ---- prologue: weights f32->bf16 (coalesced, 6 float4/thread) + PE+LN0 ----
#pragma unroll 1
  for (int j = 0; j < 6; ++j) {
    int gi = j * 131072 + bid * 256 + tid;
    const float4* src;
    int off;
    if (gi < 196608)      { src = Wq4; off = gi; }
    else if (gi < 262144) { src = Wo4; off = gi - 196608; }
    else if (gi < 524288) { src = W14; off = gi - 262144; }
    else                  { src = W24; off = gi - 524288; }
    float4 v = src[off];
    ushort4 o;
    o.x = __hip_bfloat16_raw(__float2bfloat16(v.x)).x;
    o.y = __hip_bfloat16_raw(__float2bfloat16(v.y)).x;
    o.z = __hip_bfloat16_raw(__float2bfloat16(v.z)).x;
    o.w = __hip_bfloat16_raw(__float2bfloat16(v.w)).x;
    wdst[gi] = o;
  }
  {
    const int wave = tid >> 6, lane = tid & 63;
#pragma unroll 1
    for (int rr = 0; rr < 4; ++rr) {
      int row = bid * 16 + wave * 4 + rr;
      int t = row & (TT - 1);
      const float* xr = tokens + (size_t)row * DD;
      float v[4];
      float s = 0.f;
#pragma unroll
      for (int i = 0; i < 4; ++i) {
        int d = lane + 64 * i;
        float freq = expf((float)(d & ~1) * -(9.210340371976184f / 256.f));
        float ang = (float)t * freq;
        float pe = (d & 1) ? cosf(ang) : sinf(ang);
        v[i] = xr[d] + pe;
        s += v[i];
      }
#pragma unroll
      for (int off = 32; off; off >>= 1) s += __shfl_xor(s, off, 64);
      float mu = s * (1.f / DD);
      float vs = 0.f;
#pragma unroll
      for (int i = 0; i < 4; ++i) { float dd = v[i] - mu; vs = fmaf(dd, dd, vs); }
#pragma unroll
      for (int off = 32; off; off >>= 1) vs += __shfl_xor(vs, off, 64);
      float rr2 = rsqrtf(vs * (1.f / DD) + 1e-5f);
#pragma unroll
      for (int i = 0; i < 4; ++i) {
        int d = lane + 64 * i;
        x[(size_t)row * DD + d] = v[i];
        sb[(size_t)row * DD + d] = __float2bfloat16((v[i] - mu) * rr2 * ln1g[d] + ln1b[d]);
      }
    }
  }
  gbar(bar);

  const bf16* wqb = (const bf16*)wdst;
  const bf16* wob = wqb + (size_t)NL * 3 * DD * DD;
  const bf16* w1b = wob + (size_t)NL * DD * DD;
  const bf16* w2b = w1b + (size_t)NL * FF * DD;

#pragma unroll 1
  for (int l = 0; l < NL; ++l) {
    // qkv: 128x96 tiles, (64 m) x (8 n) = 512
    gemm_stage<4, 3, 256, 0, 0>(sm, bid, 8, sb, wqb + (size_t)l * 768 * DD,
                                bqkv + l * 768, big, 768);
    gbar(bar);
    attn_stage(sm, bid, big, sb);
    gbar(bar);
    woln_stage(sm, bid, sb, wob + (size_t)l * DD * DD, bo + l * DD, x,
               ln2g + l * DD, ln2b + l * DD, x, sb);
    gbar(bar);
    // W1+gelu: 128x128 tiles, (64 m) x (8 n) = 512
    gemm_stage<4, 4, 256, 1, 0>(sm, bid, 8, sb, w1b + (size_t)l * FF * DD,
                                b1 + l * FF, big, FF);
    gbar(bar);
    // W2: 64x64 tiles, (128 m) x (4 n) = 512, fp32 out
    gemm_stage<2, 2, 1024, 0, 1>(sm, bid, 4, big, w2b + (size_t)l * DD * FF,
                                 b2 + l * DD, gbuf, DD);
    gbar(bar);
    if (l < NL - 1) {
      rln_stage<0>(bid, gbuf, x, ln1g + (l + 1) * DD, ln1b + (l + 1) * DD,
                   x, sb, nullptr);
      gbar(bar);
    } else {
      rln_stage<1>(bid, gbuf, x, lnfg, lnfb, nullptr, nullptr, out);
    }
  }
}

extern "C" void kernel_launch(void* const* d_in, const int* in_sizes, int n_in,
                              void* d_out, int out_size, void* d_ws, size_t ws_size,
                              hipStream_t stream) {
  const float* tokens = (const float*)d_in[0];
  const float* Wqkv = (const float*)d_in[1];
  const float* bqkv = (const float*)d_in[2];
  const float* Wo   = (const float*)d_in[3];
  const float* bo   = (const float*)d_in[4];
  const float* W1   = (const float*)d_in[5];
  const float* b1   = (const float*)d_in[6];
  const float* W2   = (const float*)d_in[7];
  const float* b2   = (const float*)d_in[8];
  const float* ln1g = (const float*)d_in[9];
  const float* ln1b = (const float*)d_in[10];
  const float* ln2g = (const float*)d_in[11];
  const float* ln2b = (const float*)d_in[12];
  const float* lnfg = (const float*)d_in[13];
  const float* lnfb = (const float*)d_in[14];
  float* out = (float*)d_out;

  const int M = BB * TT;                 // 8192
  const int ND = M * DD;                 // 2097152

  float* x = (float*)d_ws;                                   // 8 MB
  bf16* sb  = (bf16*)(x + ND);                               // 4 MB
  bf16* big = sb + (size_t)M * DD;                           // 16 MB
  bf16* wqb = big + (size_t)M * FF;                          // weights 6 MB
  bf16* w2end = wqb + (size_t)NL * (3 * DD * DD + DD * DD + 2 * FF * DD);
  float* gbuf = (float*)w2end;                               // 8 MB
  unsigned* bar = (unsigned*)(gbuf + ND);                    // 8 B

  hipMemsetAsync(bar, 0, 2 * sizeof(unsigned), stream);

  mega_kernel<<<NB, 256, 0, stream>>>(
      (const float4*)Wqkv, (const float4*)Wo, (const float4*)W1,
      (const float4*)W2, tokens, bqkv, bo, b1, b2,
      ln1g, ln1b, ln2g, ln2b, lnfg, lnfb,
      x, sb, big, (ushort4*)wqb, gbuf, out, bar);
}

// Round 14
// 354.504 us; speedup vs baseline: 5.1476x; 5.1476x over previous
//
#include <hip/hip_runtime.h>
#include <hip/hip_bf16.h>
#include <math.h>

#define BB 4
#define TT 2048
#define DD 256
#define FF 1024
#define NL 4

typedef __bf16 bf16x8 __attribute__((ext_vector_type(8)));
typedef float f32x4 __attribute__((ext_vector_type(4)));
typedef __hip_bfloat16 bf16;

__device__ __forceinline__ void stage16(const bf16* gp, bf16* lp) {
  __builtin_amdgcn_global_load_lds(
      (const __attribute__((address_space(1))) unsigned int*)gp,
      (__attribute__((address_space(3))) unsigned int*)lp, 16, 0, 0);
}

// fast exact-GELU: 0.5x(1+erf(x/sqrt2)), erf via A&S 7.1.26 (|err|<1.5e-7)
__device__ __forceinline__ float gelu_f(float v) {
  float x = fabsf(v) * 0.70710678118654752f;
  float t = 1.0f / fmaf(0.3275911f, x, 1.0f);
  float p = t * fmaf(t, fmaf(t, fmaf(t, fmaf(t, 1.061405429f, -1.453152027f),
                                     1.421413741f), -0.284496736f), 0.254829592f);
  float erfv = copysignf(1.0f - p * __expf(-x * x), v);
  return 0.5f * v * (1.0f + erfv);
}

// ---------------- prologue: weight f32->bf16 (blocks 0..3071) + PE+LN0 (rest) ----
__global__ __launch_bounds__(256) void prologue_kernel(
    const float4* __restrict__ wq, const float4* __restrict__ wo,
    const float4* __restrict__ w1, const float4* __restrict__ w2,
    ushort4* __restrict__ dst,
    const float* __restrict__ tokens, const float* __restrict__ g,
    const float* __restrict__ b, float* __restrict__ x,
    bf16* __restrict__ sb) {
  if (blockIdx.x < 3072) {
    int gi = blockIdx.x * 256 + threadIdx.x;
    const float4* src;
    int off;
    if (gi < 196608)      { src = wq; off = gi; }
    else if (gi < 262144) { src = wo; off = gi - 196608; }
    else if (gi < 524288) { src = w1; off = gi - 262144; }
    else                  { src = w2; off = gi - 524288; }
    float4 v = src[off];
    ushort4 o;
    o.x = __hip_bfloat16_raw(__float2bfloat16(v.x)).x;
    o.y = __hip_bfloat16_raw(__float2bfloat16(v.y)).x;
    o.z = __hip_bfloat16_raw(__float2bfloat16(v.z)).x;
    o.w = __hip_bfloat16_raw(__float2bfloat16(v.w)).x;
    dst[gi] = o;
    return;
  }
  int row = (blockIdx.x - 3072) * 4 + (threadIdx.x >> 6);
  int lane = threadIdx.x & 63;
  int t = row & (TT - 1);
  const float* xr = tokens + (size_t)row * DD;
  float v[4];
  float s = 0.f;
#pragma unroll
  for (int i = 0; i < 4; ++i) {
    int d = lane + 64 * i;
    float freq = expf((float)(d & ~1) * -(9.210340371976184f / 256.f));
    float ang = (float)t * freq;
    float pe = (d & 1) ? cosf(ang) : sinf(ang);
    v[i] = xr[d] + pe;
    s += v[i];
  }
#pragma unroll
  for (int off = 32; off; off >>= 1) s += __shfl_xor(s, off, 64);
  float mu = s * (1.f / DD);
  float vs = 0.f;
#pragma unroll
  for (int i = 0; i < 4; ++i) { float dd = v[i] - mu; vs = fmaf(dd, dd, vs); }
#pragma unroll
  for (int off = 32; off; off >>= 1) vs += __shfl_xor(vs, off, 64);
  float rr = rsqrtf(vs * (1.f / DD) + 1e-5f);
#pragma unroll
  for (int i = 0; i < 4; ++i) {
    int d = lane + 64 * i;
    x[(size_t)row * DD + d] = v[i];
    sb[(size_t)row * DD + d] = __float2bfloat16((v[i] - mu) * rr * g[d] + b[d]);
  }
}

// ---------------- bf16 MFMA GEMM, chunked LDS, XCD-aware tile swizzle ----------
// 1D grid = nM*nN blocks. xcd = bid&7 owns m-tiles [xcd*nM/8, (xcd+1)*nM/8):
// all nN n-tiles of an m-tile run on ONE XCD -> A-rows fetched into one L2.
// Tile 32MWx32NW, BK template (chunked [c][row][32]). OUTF: 0=bf16, 1=fp32.
template <int MW, int NW, int BK, int KTOT, int ACT, int OUTF>
__global__ __launch_bounds__(256) void mgemm_kernel(
    const bf16* __restrict__ A, const bf16* __restrict__ B,
    const float* __restrict__ bias, void* __restrict__ Cout,
    int N, int nN, int nM) {
  constexpr int BM = 32 * MW, BN = 32 * NW, ROWS = BM + BN;
  constexpr int NCH = BK / 32;
  constexpr int CHB = ROWS * 32;
  constexpr int RG = ROWS / 16;
  constexpr int NST = NCH * RG;
  __shared__ __align__(16) bf16 sm[NCH * CHB];
  const int tid = threadIdx.x;
  const int wave = tid >> 6, lane = tid & 63;
  const int bid = blockIdx.x;
  const int xcd = bid & 7, kk = bid >> 3;
  const int mt = xcd * (nM >> 3) + kk / nN;
  const int nt = kk - (kk / nN) * nN;
  const int m0 = mt * BM, n0 = nt * BN;
  const int wm = (wave >> 1) * (16 * MW), wn = (wave & 1) * (16 * NW);
  const int quad = lane >> 4, lr = lane & 15;
  const int srow = lane >> 2, scol = (lane & 3) * 8;

  f32x4 acc[MW][NW] = {};

  for (int kt = 0; kt < KTOT; kt += BK) {
    __syncthreads();
#pragma unroll
    for (int i = 0; i < NST / 4; ++i) {
      int inst = i * 4 + wave;
      int c = inst / RG, grp = inst - c * RG;
      int r = grp * 16 + srow;
      const bf16* gp =
          (r < BM) ? (A + (size_t)(m0 + r) * KTOT + kt + c * 32 + scol)
                   : (B + (size_t)(n0 + (r - BM)) * KTOT + kt + c * 32 + scol);
      stage16(gp, sm + c * CHB + grp * 512);
    }
    __syncthreads();
#pragma unroll
    for (int c = 0; c < NCH; ++c) {
      bf16x8 af[MW], bfr[NW];
#pragma unroll
      for (int mi = 0; mi < MW; ++mi)
        af[mi] = *(const bf16x8*)(sm + c * CHB + (wm + mi * 16 + lr) * 32 + quad * 8);
#pragma unroll
      for (int ni = 0; ni < NW; ++ni)
        bfr[ni] = *(const bf16x8*)(sm + c * CHB + (BM + wn + ni * 16 + lr) * 32 + quad * 8);
#pragma unroll
      for (int mi = 0; mi < MW; ++mi)
#pragma unroll
        for (int ni = 0; ni < NW; ++ni)
          acc[mi][ni] = __builtin_amdgcn_mfma_f32_16x16x32_bf16(
              af[mi], bfr[ni], acc[mi][ni], 0, 0, 0);
    }
  }

#pragma unroll
  for (int mi = 0; mi < MW; ++mi)
#pragma unroll
    for (int ni = 0; ni < NW; ++ni) {
      int col = n0 + wn + ni * 16 + lr;
      float bv = bias[col];
#pragma unroll
      for (int r = 0; r < 4; ++r) {
        int row = m0 + wm + mi * 16 + quad * 4 + r;
        float v = acc[mi][ni][r] + bv;
        if (ACT == 1) v = gelu_f(v);
        if (OUTF) ((float*)Cout)[(size_t)row * N + col] = v;
        else ((bf16*)Cout)[(size_t)row * N + col] = __float2bfloat16(v);
      }
    }
}

// ---------------- bf16 GEMM, N=256 full-row, fused residual+LN (Wo path only) ----
template <int KTOT>
__global__ __launch_bounds__(256) void mgemm_ln_kernel(
    const bf16* __restrict__ A, const bf16* __restrict__ B,
    const float* __restrict__ bias, const float* __restrict__ res,
    const float* __restrict__ g, const float* __restrict__ bb,
    float* __restrict__ xout, bf16* __restrict__ yout) {
  constexpr int BM = 32, ROWS = BM + 256;
  constexpr int BK = 64, NCH = BK / 32;
  constexpr int CHB = ROWS * 32;
  constexpr int RG = ROWS / 16;
  constexpr int NST = NCH * RG;
  __shared__ __align__(16) bf16 sm[NCH * CHB];
  __shared__ float red1[4][BM], red2[4][BM];
  const int tid = threadIdx.x;
  const int wave = tid >> 6, lane = tid & 63;
  const int quad = lane >> 4, lr = lane & 15;
  const int m0 = blockIdx.x * BM;
  const int srow = lane >> 2, scol = (lane & 3) * 8;

  f32x4 acc[2][4] = {};

  for (int kt = 0; kt < KTOT; kt += BK) {
    __syncthreads();
#pragma unroll
    for (int i = 0; i < NST / 4; ++i) {
      int inst = i * 4 + wave;
      int c = inst / RG, grp = inst - c * RG;
      int r = grp * 16 + srow;
      const bf16* gp =
          (r < BM) ? (A + (size_t)(m0 + r) * KTOT + kt + c * 32 + scol)
                   : (B + (size_t)(r - BM) * KTOT + kt + c * 32 + scol);
      stage16(gp, sm + c * CHB + grp * 512);
    }
    __syncthreads();
#pragma unroll
    for (int c = 0; c < NCH; ++c) {
      bf16x8 af[2], bfr[4];
#pragma unroll
      for (int mi = 0; mi < 2; ++mi)
        af[mi] = *(const bf16x8*)(sm + c * CHB + (mi * 16 + lr) * 32 + quad * 8);
#pragma unroll
      for (int ni = 0; ni < 4; ++ni)
        bfr[ni] = *(const bf16x8*)(sm + c * CHB + (BM + wave * 64 + ni * 16 + lr) * 32 + quad * 8);
#pragma unroll
      for (int mi = 0; mi < 2; ++mi)
#pragma unroll
        for (int ni = 0; ni < 4; ++ni)
          acc[mi][ni] = __builtin_amdgcn_mfma_f32_16x16x32_bf16(
              af[mi], bfr[ni], acc[mi][ni], 0, 0, 0);
    }
  }

  float v[2][4][4];
  float s1[2][4] = {}, s2[2][4] = {};
#pragma unroll
  for (int mi = 0; mi < 2; ++mi)
#pragma unroll
    for (int ni = 0; ni < 4; ++ni) {
      int col = wave * 64 + ni * 16 + lr;
      float bv = bias[col];
#pragma unroll
      for (int r = 0; r < 4; ++r) {
        int row = m0 + mi * 16 + quad * 4 + r;
        float val = acc[mi][ni][r] + bv + res[(size_t)row * DD + col];
        v[mi][ni][r] = val;
        s1[mi][r] += val;
        s2[mi][r] = fmaf(val, val, s2[mi][r]);
      }
    }
#pragma unroll
  for (int mi = 0; mi < 2; ++mi)
#pragma unroll
    for (int r = 0; r < 4; ++r) {
#pragma unroll
      for (int off = 8; off; off >>= 1) {
        s1[mi][r] += __shfl_xor(s1[mi][r], off, 64);
        s2[mi][r] += __shfl_xor(s2[mi][r], off, 64);
      }
    }
  if (lr == 0) {
#pragma unroll
    for (int mi = 0; mi < 2; ++mi)
#pragma unroll
      for (int r = 0; r < 4; ++r) {
        red1[wave][mi * 16 + quad * 4 + r] = s1[mi][r];
        red2[wave][mi * 16 + quad * 4 + r] = s2[mi][r];
      }
  }
  __syncthreads();
#pragma unroll
  for (int mi = 0; mi < 2; ++mi)
#pragma unroll
    for (int r = 0; r < 4; ++r) {
      int rl = mi * 16 + quad * 4 + r;
      float ssum = red1[0][rl] + red1[1][rl] + red1[2][rl] + red1[3][rl];
      float qsum = red2[0][rl] + red2[1][rl] + red2[2][rl] + red2[3][rl];
      float mu = ssum * (1.f / DD);
      float var = qsum * (1.f / DD) - mu * mu;
      float rr = rsqrtf(var + 1e-5f);
      int row = m0 + rl;
#pragma unroll
      for (int ni = 0; ni < 4; ++ni) {
        int col = wave * 64 + ni * 16 + lr;
        float y = (v[mi][ni][r] - mu) * rr * g[col] + bb[col];
        yout[(size_t)row * DD + col] = __float2bfloat16(y);
        xout[(size_t)row * DD + col] = v[mi][ni][r];
      }
    }
}

// ---------------- residual + LayerNorm (elementwise, 1 wave/row, bf16 gout) ----
template <int FIN>
__global__ __launch_bounds__(256) void rln_kernel(
    const bf16* __restrict__ go, const float* __restrict__ xin,
    const float* __restrict__ g, const float* __restrict__ b,
    float* __restrict__ xout, bf16* __restrict__ sbout,
    float* __restrict__ out) {
  int row = blockIdx.x * 4 + (threadIdx.x >> 6);
  int lane = threadIdx.x & 63;
  const bf16* gr = go + (size_t)row * DD;
  const float* xr = xin + (size_t)row * DD;
  float v[4];
  float s = 0.f;
#pragma unroll
  for (int i = 0; i < 4; ++i) {
    int d = lane + 64 * i;
    v[i] = __bfloat162float(gr[d]) + xr[d];
    s += v[i];
  }
#pragma unroll
  for (int off = 32; off; off >>= 1) s += __shfl_xor(s, off, 64);
  float mu = s * (1.f / DD);
  float vs = 0.f;
#pragma unroll
  for (int i = 0; i < 4; ++i) { float dd = v[i] - mu; vs = fmaf(dd, dd, vs); }
#pragma unroll
  for (int off = 32; off; off >>= 1) vs += __shfl_xor(vs, off, 64);
  float rr = rsqrtf(vs * (1.f / DD) + 1e-5f);
#pragma unroll
  for (int i = 0; i < 4; ++i) {
    int d = lane + 64 * i;
    float y = (v[i] - mu) * rr * g[d] + b[d];
    if (FIN) {
      out[(size_t)row * DD + d] = y;
    } else {
      xout[(size_t)row * DD + d] = v[i];
      sbout[(size_t)row * DD + d] = __float2bfloat16(y);
    }
  }
}

// ---------------- sliding-window attention, MFMA (R9/R12, unchanged) ----------------
__global__ __launch_bounds__(256) void attn_kernel(const bf16* __restrict__ qkv,
                                                   bf16* __restrict__ o) {
  __shared__ __align__(16) bf16 KsPs[128 * 72];
  __shared__ __align__(16) bf16 Vt[64 * 136];
  const int bh = blockIdx.y;
  const int b = bh >> 2, h = bh & 3;
  const int t0 = blockIdx.x * 64;
  const int sbase = t0 - 63;
  const int tid = threadIdx.x;

  const bf16* kb = qkv + (size_t)(b * TT) * 768 + 256 + h * 64;
  const bf16* vb = kb + 256;
  union U8 { uint4 u; bf16 hx[8]; };
#pragma unroll
  for (int it = 0; it < 4; ++it) {
    int f = tid + it * 256;
    int si = f >> 3;
    int c8 = f & 7;
    int s = sbase + si;
    U8 kr, vr;
    kr.u = make_uint4(0, 0, 0, 0); vr.u = make_uint4(0, 0, 0, 0);
    if (s >= 0 && s < TT) {
      kr.u = *(const uint4*)&kb[(size_t)s * 768 + 8 * c8];
      vr.u = *(const uint4*)&vb[(size_t)s * 768 + 8 * c8];
    }
    *(uint4*)&KsPs[si * 72 + c8 * 8] = kr.u;
    int pc = (si >> 3) ^ c8;
#pragma unroll
    for (int j = 0; j < 8; ++j) Vt[(c8 * 8 + j) * 136 + pc * 8 + (si & 7)] = vr.hx[j];
  }
  __syncthreads();

  const int wave = tid >> 6, lane = tid & 63;
  const int quad = lane >> 4, lr = lane & 15;

  const bf16* qrow = qkv + (size_t)(b * TT + t0 + wave * 16 + lr) * 768 + h * 64;
  bf16x8 qa0 = *(const bf16x8*)(qrow + quad * 8);
  bf16x8 qa1 = *(const bf16x8*)(qrow + 32 + quad * 8);
  f32x4 sc[8];
#pragma unroll
  for (int c = 0; c < 8; ++c) {
    f32x4 a = {};
    bf16x8 kf0 = *(const bf16x8*)&KsPs[(c * 16 + lr) * 72 + quad * 8];
    a = __builtin_amdgcn_mfma_f32_16x16x32_bf16(qa0, kf0, a, 0, 0, 0);
    bf16x8 kf1 = *(const bf16x8*)&KsPs[(c * 16 + lr) * 72 + 32 + quad * 8];
    a = __builtin_amdgcn_mfma_f32_16x16x32_bf16(qa1, kf1, a, 0, 0, 0);
    sc[c] = a;
  }
  __syncthreads();

#pragma unroll
  for (int reg = 0; reg < 4; ++reg) {
    int dt = wave * 16 + quad * 4 + reg;
    float pv[8];
    float mx = -1e30f;
#pragma unroll
    for (int c = 0; c < 8; ++c) {
      int si = c * 16 + lr;
      float v = sc[c][reg] * 0.125f;
      bool ok = (si >= dt) && (si <= dt + 63) && (sbase + si >= 0);
      v = ok ? v : -1e30f;
      pv[c] = v;
      mx = fmaxf(mx, v);
    }
#pragma unroll
    for (int off = 8; off; off >>= 1) mx = fmaxf(mx, __shfl_xor(mx, off, 64));
    float l = 0.f;
#pragma unroll
    for (int c = 0; c < 8; ++c) { float e = __expf(pv[c] - mx); pv[c] = e; l += e; }
#pragma unroll
    for (int off = 8; off; off >>= 1) l += __shfl_xor(l, off, 64);
    float rinv = 1.f / l;
#pragma unroll
    for (int c = 0; c < 8; ++c)
      KsPs[(wave * 16 + quad * 4 + reg) * 136 + c * 16 + lr] = __float2bfloat16(pv[c] * rinv);
  }

  bf16* obase = o + (size_t)(b * TT) * DD + h * 64;
#pragma unroll
  for (int ct = 0; ct < 4; ++ct) {
    f32x4 acc = {};
#pragma unroll
    for (int kk = 0; kk < 4; ++kk) {
      bf16x8 pa = *(const bf16x8*)&KsPs[(wave * 16 + lr) * 136 + kk * 32 + quad * 8];
      int dd = ct * 16 + lr;
      bf16x8 vf = *(const bf16x8*)&Vt[dd * 136 + (((kk * 4 + quad) ^ (dd >> 3)) * 8)];
      acc = __builtin_amdgcn_mfma_f32_16x16x32_bf16(pa, vf, acc, 0, 0, 0);
    }
#pragma unroll
    for (int reg = 0; reg < 4; ++reg) {
      int t = t0 + wave * 16 + quad * 4 + reg;
      obase[(size_t)t * DD + ct * 16 + lr] = __float2bfloat16(acc[reg]);
    }
  }
}

extern "C" void kernel_launch(void* const* d_in, const int* in_sizes, int n_in,
                              void* d_out, int out_size, void* d_ws, size_t ws_size,
                              hipStream_t stream) {
  const float* tokens = (const float*)d_in[0];
  const float* Wqkv = (const float*)d_in[1];
  const float* bqkv = (const float*)d_in[2];
  const float* Wo   = (const float*)d_in[3];
  const float* bo   = (const float*)d_in[4];
  const float* W1   = (const float*)d_in[5];
  const float* b1   = (const float*)d_in[6];
  const float* W2   = (const float*)d_in[7];
  const float* b2   = (const float*)d_in[8];
  const float* ln1g = (const float*)d_in[9];
  const float* ln1b = (const float*)d_in[10];
  const float* ln2g = (const float*)d_in[11];
  const float* ln2b = (const float*)d_in[12];
  const float* lnfg = (const float*)d_in[13];
  const float* lnfb = (const float*)d_in[14];
  float* out = (float*)d_out;

  const int M = BB * TT;                 // 8192
  const int ND = M * DD;

  float* x = (float*)d_ws;
  bf16* sb  = (bf16*)(x + ND);
  bf16* big = sb + (size_t)M * DD;
  bf16* wqb = big + (size_t)M * FF;
  bf16* wob = wqb + (size_t)NL * 3 * DD * DD;
  bf16* w1b = wob + (size_t)NL * DD * DD;
  bf16* w2b = w1b + (size_t)NL * FF * DD;
  bf16* gbuf = w2b + (size_t)NL * DD * FF;    // W2 raw out, M*256 bf16

  prologue_kernel<<<3072 + M / 4, 256, 0, stream>>>(
      (const float4*)Wqkv, (const float4*)Wo, (const float4*)W1,
      (const float4*)W2, (ushort4*)wqb, tokens, ln1g, ln1b, x, sb);

  // layer-0 qkv: 64x128 tiles, BK=128, XCD-swizzled, 768 blocks
  mgemm_kernel<2, 4, 128, 256, 0, 0><<<768, 256, 0, stream>>>(
      sb, wqb, bqkv, big, 768, 6, 128);

  for (int l = 0; l < NL; ++l) {
    attn_kernel<<<dim3(TT / 64, BB * 4), 256, 0, stream>>>(big, sb);
    // Wo + residual + ln2 (B small: keep fused)
    mgemm_ln_kernel<256><<<M / 32, 256, 0, stream>>>(
        sb, wob + (size_t)l * DD * DD, bo + l * DD, x,
        ln2g + l * DD, ln2b + l * DD, x, sb);
    // W1 + GELU: 64x128 tiles, BK=128, 1024 blocks
    mgemm_kernel<2, 4, 128, 256, 1, 0><<<1024, 256, 0, stream>>>(
        sb, w1b + (size_t)l * FF * DD, b1 + l * FF, big, FF, 8, 128);
    // W2: 64x64 tiles, BK=128, 512 blocks, bf16 out
    mgemm_kernel<2, 2, 128, 1024, 0, 0><<<512, 256, 0, stream>>>(
        big, w2b + (size_t)l * DD * FF, b2 + l * DD, gbuf, DD, 4, 128);
    if (l < NL - 1) {
      rln_kernel<0><<<M / 4, 256, 0, stream>>>(
          gbuf, x, ln1g + (l + 1) * DD, ln1b + (l + 1) * DD, x, sb, nullptr);
      mgemm_kernel<2, 4, 128, 256, 0, 0><<<768, 256, 0, stream>>>(
          sb, wqb + (size_t)(l + 1) * 768 * DD, bqkv + (l + 1) * 768, big, 768, 6, 128);
    } else {
      rln_kernel<1><<<M / 4, 256, 0, stream>>>(
          gbuf, x, lnfg, lnfb, nullptr, nullptr, out);
    }
  }
}